// Round 2
// baseline (424.657 us; speedup 1.0000x reference)
//
#include <hip/hip_runtime.h>

#define NTOK 4096
#define DIM  32
#define NBH  32

static __device__ __forceinline__ void fma4(float4& a, float s, const float4 b) {
    a.x += s * b.x; a.y += s * b.y; a.z += s * b.z; a.w += s * b.w;
}

// ---------------------------------------------------------------------------
// Kernel 1: per-(chunk, bh) partial reductions over key rows.
//   P  [NC][NBH][1024][32]  partial M2 (plain stores, coalesced)
//   S2 [NBH][1024], M1 [NBH][32][32], s1 [NBH][32], v0 [NBH][32] (atomics)
// Thread t: pc = t>>1 (0..127), eh = t&1. Pairs p = pc + 128*jj (jj=0..7):
//   j = pc&31 (fixed), i = (pc>>5) + 4*jj. e-range = eh*16 .. eh*16+15.
// ---------------------------------------------------------------------------
__global__ __launch_bounds__(256, 2)
void k1_partial(const float* __restrict__ kin, const float* __restrict__ vin,
                float* __restrict__ P, float* __restrict__ S2,
                float* __restrict__ M1, float* __restrict__ s1,
                float* __restrict__ v0, int rows_per_chunk)
{
    const int bh    = blockIdx.y;
    const int chunk = blockIdx.x;
    const int t     = threadIdx.x;

    __shared__ float ks[128][DIM];
    __shared__ float vs[128][DIM];

    const int pc    = t >> 1;
    const int eh    = t & 1;
    const int e0    = eh * 16;
    const int jfix  = pc & 31;
    const int ibase = pc >> 5;

    float4 acc4[8][4];
    #pragma unroll
    for (int a = 0; a < 8; ++a)
        #pragma unroll
        for (int c = 0; c < 4; ++c) acc4[a][c] = make_float4(0.f, 0.f, 0.f, 0.f);
    float ss[8] = {0.f,0.f,0.f,0.f,0.f,0.f,0.f,0.f};

    const int dm = t >> 3;   // M1 row 0..31
    const int em = t & 7;    // M1 col-quad 0..7
    float4 m1a = make_float4(0.f,0.f,0.f,0.f);
    float  s1a = 0.f;
    float4 v0a = make_float4(0.f,0.f,0.f,0.f);

    const size_t rowbase = (size_t)bh * NTOK + (size_t)chunk * rows_per_chunk;
    const int nsub = rows_per_chunk >> 7;

    for (int sub = 0; sub < nsub; ++sub) {
        __syncthreads();
        const float4* kg = (const float4*)(kin + (rowbase + (size_t)sub * 128) * DIM);
        const float4* vg = (const float4*)(vin + (rowbase + (size_t)sub * 128) * DIM);
        float4* ksd = (float4*)&ks[0][0];
        float4* vsd = (float4*)&vs[0][0];
        #pragma unroll
        for (int r = 0; r < 4; ++r) {
            ksd[t + 256*r] = kg[t + 256*r];
            vsd[t + 256*r] = vg[t + 256*r];
        }
        __syncthreads();

        for (int n = 0; n < 128; ++n) {
            const float kj = ks[n][jfix];
            const float4* vr = (const float4*)&vs[n][0];
            float4 vv0 = vr[eh*4 + 0];
            float4 vv1 = vr[eh*4 + 1];
            float4 vv2 = vr[eh*4 + 2];
            float4 vv3 = vr[eh*4 + 3];
            float ki[8];
            #pragma unroll
            for (int jj = 0; jj < 8; ++jj) ki[jj] = ks[n][ibase + 4*jj];
            #pragma unroll
            for (int jj = 0; jj < 8; ++jj) {
                const float kk = ki[jj] * kj;
                ss[jj] += kk;
                fma4(acc4[jj][0], kk, vv0);
                fma4(acc4[jj][1], kk, vv1);
                fma4(acc4[jj][2], kk, vv2);
                fma4(acc4[jj][3], kk, vv3);
            }
        }
        // M1 / s1 / v0 pass over the same tile
        for (int n = 0; n < 128; ++n) {
            const float kd = ks[n][dm];
            const float4 vq = ((const float4*)&vs[n][0])[em];
            fma4(m1a, kd, vq);
            if (em == 0) s1a += kd;
            if (dm == 0) { v0a.x += vq.x; v0a.y += vq.y; v0a.z += vq.z; v0a.w += vq.w; }
        }
    }

    // coalesced partial-M2 stores: lane-consecutive addresses per (jj,c)
    float* Pb = P + ((size_t)chunk * NBH + bh) * 1024 * DIM;
    #pragma unroll
    for (int jj = 0; jj < 8; ++jj) {
        const int p = pc + 128*jj;
        float4* dst = (float4*)(Pb + (size_t)p * DIM + e0);
        dst[0] = acc4[jj][0];
        dst[1] = acc4[jj][1];
        dst[2] = acc4[jj][2];
        dst[3] = acc4[jj][3];
        // S2 ownership: eh==0 only — both eh halves compute the identical
        // ss[jj]; adding from both double-counts S2 (round-1 bug: outputs
        // scaled by ~0.5 because the PSD q2.S2 term dominates the denom).
        if (eh == 0) atomicAdd(&S2[bh*1024 + p], ss[jj]);
    }
    atomicAdd(&M1[(bh*DIM + dm)*DIM + em*4 + 0], m1a.x);
    atomicAdd(&M1[(bh*DIM + dm)*DIM + em*4 + 1], m1a.y);
    atomicAdd(&M1[(bh*DIM + dm)*DIM + em*4 + 2], m1a.z);
    atomicAdd(&M1[(bh*DIM + dm)*DIM + em*4 + 3], m1a.w);
    if (em == 0) atomicAdd(&s1[bh*DIM + dm], s1a);
    if (dm == 0) {
        atomicAdd(&v0[bh*DIM + em*4 + 0], v0a.x);
        atomicAdd(&v0[bh*DIM + em*4 + 1], v0a.y);
        atomicAdd(&v0[bh*DIM + em*4 + 2], v0a.z);
        atomicAdd(&v0[bh*DIM + em*4 + 3], v0a.w);
    }
}

// ---------------------------------------------------------------------------
// Kernel 1b: reduce NC partial M2 planes -> final M2 [NBH][1024][32]
// ---------------------------------------------------------------------------
__global__ __launch_bounds__(256)
void k1_reduce(const float* __restrict__ P, float* __restrict__ M2, int NCc)
{
    const size_t g = (size_t)blockIdx.x * 256 + threadIdx.x;  // float4 index
    const float4* P4 = (const float4*)P;
    float4 a = P4[g];
    for (int c = 1; c < NCc; ++c) {
        const float4 b = P4[(size_t)c * 262144 + g];
        a.x += b.x; a.y += b.y; a.z += b.z; a.w += b.w;
    }
    ((float4*)M2)[g] = a;
}

// ---------------------------------------------------------------------------
// Kernel 2: per query n:
//   out[e] = (v0[e] + q.M1 + 0.5*q2.M2) / (4096 + q.s1 + 0.5*q2.S2)
// block: 128 threads, 256 queries (2 per thread). q rows in padded LDS.
// M2 rows read from global (same-line all-lane broadcast -> L1/L2).
// ---------------------------------------------------------------------------
__global__ __launch_bounds__(128)
void k2_apply(const float* __restrict__ q, const float* __restrict__ M2,
              const float* __restrict__ M1, const float* __restrict__ S2,
              const float* __restrict__ s1, const float* __restrict__ v0,
              float* __restrict__ out)
{
    const int bh = blockIdx.y;
    const int t  = threadIdx.x;
    const int qbase = blockIdx.x * 256;

    __shared__ float qsA[128][33];
    __shared__ float qsB[128][33];
    __shared__ float S2l[1024];
    __shared__ float M1l[1024];
    __shared__ float s1l[DIM];
    __shared__ float v0l[DIM];

    const float* qg = q + ((size_t)bh * NTOK + qbase) * DIM;
    #pragma unroll
    for (int r = 0; r < 16; ++r) {
        const int i4 = t + 128*r;              // 0..2047 float4s = 256 rows
        const float4 val = ((const float4*)qg)[i4];
        const int row = i4 >> 3, c4 = (i4 & 7) * 4;
        float* dst = (row < 128) ? &qsA[row][c4] : &qsB[row-128][c4];
        dst[0] = val.x; dst[1] = val.y; dst[2] = val.z; dst[3] = val.w;
    }
    {
        const float4* S2g = (const float4*)(S2 + bh*1024);
        const float4* M1g = (const float4*)(M1 + bh*1024);
        ((float4*)S2l)[t]       = S2g[t];
        ((float4*)S2l)[t + 128] = S2g[t + 128];
        ((float4*)M1l)[t]       = M1g[t];
        ((float4*)M1l)[t + 128] = M1g[t + 128];
        if (t < DIM) { s1l[t] = s1[bh*DIM + t]; v0l[t] = v0[bh*DIM + t]; }
    }
    __syncthreads();

    float4 a0[8], a1[8];
    #pragma unroll
    for (int c = 0; c < 8; ++c) {
        a0[c] = make_float4(0.f,0.f,0.f,0.f);
        a1[c] = make_float4(0.f,0.f,0.f,0.f);
    }
    float d0 = 0.f, d1 = 0.f;

    const float* Tg = M2 + (size_t)bh * 1024 * DIM;
    for (int i = 0; i < 32; ++i) {
        const float qi0 = qsA[t][i];
        const float qi1 = qsB[t][i];
        #pragma unroll 4
        for (int j = 0; j < 32; ++j) {
            const float qq0 = qi0 * qsA[t][j];
            const float qq1 = qi1 * qsB[t][j];
            const float s2v = S2l[i*32 + j];
            d0 += qq0 * s2v;
            d1 += qq1 * s2v;
            const float4* Trow = (const float4*)(Tg + (size_t)(i*32 + j) * DIM);
            #pragma unroll
            for (int c = 0; c < 8; ++c) {
                const float4 tv = Trow[c];
                fma4(a0[c], qq0, tv);
                fma4(a1[c], qq1, tv);
            }
        }
    }

    // apply A2 = 0.5 to the quadratic terms
    #pragma unroll
    for (int c = 0; c < 8; ++c) {
        a0[c].x *= 0.5f; a0[c].y *= 0.5f; a0[c].z *= 0.5f; a0[c].w *= 0.5f;
        a1[c].x *= 0.5f; a1[c].y *= 0.5f; a1[c].z *= 0.5f; a1[c].w *= 0.5f;
    }
    d0 *= 0.5f; d1 *= 0.5f;

    // linear terms (A1 = 1): q.M1 into numerator, q.s1 into denominator
    #pragma unroll 4
    for (int dd = 0; dd < 32; ++dd) {
        const float c0 = qsA[t][dd];
        const float c1 = qsB[t][dd];
        d0 += c0 * s1l[dd];
        d1 += c1 * s1l[dd];
        const float4* Mr = (const float4*)&M1l[dd*32];
        #pragma unroll
        for (int c = 0; c < 8; ++c) {
            const float4 mv = Mr[c];
            fma4(a0[c], c0, mv);
            fma4(a1[c], c1, mv);
        }
    }

    // constant terms (A0 = 1)
    d0 += 4096.0f;
    d1 += 4096.0f;
    const float4* v04 = (const float4*)v0l;
    #pragma unroll
    for (int c = 0; c < 8; ++c) {
        const float4 vv = v04[c];
        a0[c].x += vv.x; a0[c].y += vv.y; a0[c].z += vv.z; a0[c].w += vv.w;
        a1[c].x += vv.x; a1[c].y += vv.y; a1[c].z += vv.z; a1[c].w += vv.w;
    }

    const float inv0 = 1.0f / d0;
    const float inv1 = 1.0f / d1;
    float4* o0 = (float4*)(out + ((size_t)bh*NTOK + qbase + t) * DIM);
    float4* o1 = (float4*)(out + ((size_t)bh*NTOK + qbase + 128 + t) * DIM);
    #pragma unroll
    for (int c = 0; c < 8; ++c) {
        float4 r0 = a0[c], r1 = a1[c];
        r0.x *= inv0; r0.y *= inv0; r0.z *= inv0; r0.w *= inv0;
        r1.x *= inv1; r1.y *= inv1; r1.z *= inv1; r1.w *= inv1;
        o0[c] = r0;
        o1[c] = r1;
    }
}

// ---------------------------------------------------------------------------
extern "C" void kernel_launch(void* const* d_in, const int* in_sizes, int n_in,
                              void* d_out, int out_size, void* d_ws, size_t ws_size,
                              hipStream_t stream)
{
    const float* q = (const float*)d_in[0];
    const float* k = (const float*)d_in[1];
    const float* v = (const float*)d_in[2];
    float* out = (float*)d_out;
    float* ws  = (float*)d_ws;

    // pick number of reduction chunks that fits the workspace
    int NC = 16;
    while (NC > 1) {
        const size_t need = ((size_t)(NC + 1) * 1048576 + 32768 + 32768 + 1024 + 1024)
                            * sizeof(float);
        if (need <= ws_size) break;
        NC >>= 1;
    }

    const size_t M2_off = (size_t)NC * 1048576;
    const size_t M1_off = M2_off + 1048576;
    const size_t S2_off = M1_off + 32768;
    const size_t s1_off = S2_off + 32768;
    const size_t v0_off = s1_off + 1024;

    float* P   = ws;
    float* M2w = ws + M2_off;
    float* M1w = ws + M1_off;
    float* S2w = ws + S2_off;
    float* s1w = ws + s1_off;
    float* v0w = ws + v0_off;

    // zero the atomic targets (M1, S2, s1, v0 are contiguous)
    hipMemsetAsync(M1w, 0, (32768 + 32768 + 1024 + 1024) * sizeof(float), stream);

    const int rows = NTOK / NC;
    dim3 g1(NC, NBH);
    k1_partial<<<g1, 256, 0, stream>>>(k, v, P, S2w, M1w, s1w, v0w, rows);
    k1_reduce<<<1024, 256, 0, stream>>>(P, M2w, NC);
    dim3 g2(16, NBH);
    k2_apply<<<g2, 128, 0, stream>>>(q, M2w, M1w, S2w, s1w, v0w, out);
}

// Round 3
// 168.007 us; speedup vs baseline: 2.5276x; 2.5276x over previous
//
#include <hip/hip_runtime.h>

#define NTOK 4096
#define NBH  32
#define NF   1088   // features: 32 linear + 1024 quadratic + 1 const + 31 pad
#define NE   33     // stored G columns: 32 v-cols + 1 ones-col (denominator)
#define GE   48     // Gt row-count stride (rows 33..47 never written/used)

typedef _Float16 half_t;
typedef _Float16 half8 __attribute__((ext_vector_type(8)));
typedef _Float16 half4v __attribute__((ext_vector_type(4)));
typedef float f32x4 __attribute__((ext_vector_type(4)));

#define MFMA16(A,B,C) __builtin_amdgcn_mfma_f32_16x16x32_f16((A),(B),(C),0,0,0)

// ---------------------------------------------------------------------------
// T: transpose + fp32->fp16  k,v [bh][n][32] -> [bh][32][n]
// swizzled LDS tile to keep the scatter writes spread across banks.
// ---------------------------------------------------------------------------
__global__ __launch_bounds__(256)
void t_kernel(const float* __restrict__ kin, const float* __restrict__ vin,
              half_t* __restrict__ kTg, half_t* __restrict__ vTg)
{
    const int nb = blockIdx.x;     // 16 blocks of 256 n
    const int bh = blockIdx.y;
    const int t  = threadIdx.x;
    __shared__ half_t tile[32 * 272];
    const size_t inbase = ((size_t)bh * NTOK + nb * 256) * 32;

    for (int pass = 0; pass < 2; ++pass) {
        const float* src = pass ? vin : kin;
        half_t* dstg     = pass ? vTg : kTg;
        if (pass) __syncthreads();
        const float4* s4 = (const float4*)(src + inbase);
        #pragma unroll
        for (int r = 0; r < 8; ++r) {
            int f4 = t + 256 * r;
            int n = f4 >> 3, d4 = f4 & 7;
            float4 vv = s4[f4];
            int nn = n ^ ((d4 & 7) << 3);      // swizzle: s(d)=((d>>2)&7)<<3
            int d0 = d4 * 4;
            tile[(d0 + 0) * 272 + nn] = (half_t)vv.x;
            tile[(d0 + 1) * 272 + nn] = (half_t)vv.y;
            tile[(d0 + 2) * 272 + nn] = (half_t)vv.z;
            tile[(d0 + 3) * 272 + nn] = (half_t)vv.w;
        }
        __syncthreads();
        #pragma unroll
        for (int cc = 0; cc < 4; ++cc) {
            int lin = t + 256 * cc;
            int d = lin >> 5, ch = lin & 31;
            int sw = (d >> 2) & 7;
            half8 val = *(const half8*)&tile[d * 272 + ((ch ^ sw) << 3)];
            *(half8*)&dstg[((size_t)bh * 32 + d) * NTOK + nb * 256 + ch * 8] = val;
        }
    }
}

// ---------------------------------------------------------------------------
// A: G[p][e] = sum_n phi(k_n)[p] * [v_n | 1][e]  via f16 MFMA.
// A-frag[m=p][k=n]: lane(l16,quad) = kT[i][win] * kT[j][win], i fixed per
// m-tile pair, j = j0 + l16, win = 8 consecutive n. Partials to P[kc].
// ---------------------------------------------------------------------------
__global__ __launch_bounds__(256)
void a_kernel(const half_t* __restrict__ kTg, const half_t* __restrict__ vTg,
              float* __restrict__ P, int Kc)
{
    const int mb = blockIdx.x;   // 0..4 : 256 features each (mb4: only w0 real)
    const int kc = blockIdx.y;
    const int bh = blockIdx.z;
    const int t = threadIdx.x;
    const int w = t >> 6, lane = t & 63, l16 = lane & 15, quad = lane >> 4;

    __shared__ half_t kT[32 * 136];
    __shared__ half_t vT[32 * 136];

    const int pw = mb * 256 + w * 64;
    const bool active = (pw < NF);
    const int mode = (mb == 0 && w == 0) ? 1 : ((mb == 4) ? 2 : 0);
    const int i0 = (pw >= 32) ? ((pw - 32) >> 5) : 0;

    f32x4 acc[3][4];
    #pragma unroll
    for (int a = 0; a < 3; ++a)
        #pragma unroll
        for (int b = 0; b < 4; ++b)
            acc[a][b] = (f32x4){0.f, 0.f, 0.f, 0.f};

    const size_t gbase = (size_t)bh * 32 * NTOK;
    const int nPer = NTOK / Kc;
    const int nStages = nPer >> 7;

    for (int st = 0; st < nStages; ++st) {
        __syncthreads();
        const int nbase = kc * nPer + st * 128;
        #pragma unroll
        for (int c = 0; c < 2; ++c) {
            int idx = t + 256 * c;
            int row = idx >> 4, part = idx & 15;
            size_t go = gbase + (size_t)row * NTOK + nbase + part * 8;
            *(half8*)&kT[row * 136 + part * 8] = *(const half8*)&kTg[go];
            *(half8*)&vT[row * 136 + part * 8] = *(const half8*)&vTg[go];
        }
        __syncthreads();
        if (!active) continue;
        #pragma unroll
        for (int kk = 0; kk < 4; ++kk) {
            const int win = kk * 32 + quad * 8;
            half8 bf0 = *(const half8*)&vT[l16 * 136 + win];
            half8 bf1 = *(const half8*)&vT[(l16 + 16) * 136 + win];
            half_t onec = (l16 == 0) ? (half_t)1 : (half_t)0;
            half8 bf2 = {onec, onec, onec, onec, onec, onec, onec, onec};
            half8 kj0 = *(const half8*)&kT[l16 * 136 + win];
            half8 kj1 = *(const half8*)&kT[(l16 + 16) * 136 + win];
            half8 af[4];
            bool skip3 = false;
            if (mode == 1) {            // p 0..63: linear tiles + i=0 quads
                half8 ki = *(const half8*)&kT[0 * 136 + win];
                af[0] = kj0; af[1] = kj1;
                af[2] = ki * kj0; af[3] = ki * kj1;
            } else if (mode == 2) {     // p 1024..1087: i=31, const, zero
                half8 ki = *(const half8*)&kT[31 * 136 + win];
                af[0] = ki * kj0; af[1] = ki * kj1;
                af[2] = bf2;            // const feature row 1056 (l16==0)
                af[3] = bf2;            // unused (skip3)
                skip3 = true;
            } else {
                half8 kia = *(const half8*)&kT[i0 * 136 + win];
                half8 kib = *(const half8*)&kT[(i0 + 1) * 136 + win];
                af[0] = kia * kj0; af[1] = kia * kj1;
                af[2] = kib * kj0; af[3] = kib * kj1;
            }
            #pragma unroll
            for (int mt = 0; mt < 4; ++mt) {
                if (skip3 && mt == 3) continue;
                acc[0][mt] = MFMA16(af[mt], bf0, acc[0][mt]);
                acc[1][mt] = MFMA16(af[mt], bf1, acc[1][mt]);
                acc[2][mt] = MFMA16(af[mt], bf2, acc[2][mt]);
            }
        }
    }
    if (active) {
        float* Pb = P + ((size_t)kc * NBH + bh) * NE * NF;
        #pragma unroll
        for (int mt = 0; mt < 4; ++mt) {
            int p0 = pw + mt * 16 + quad * 4;    // C rows (=p) are quad*4+reg
            *(f32x4*)&Pb[(size_t)l16 * NF + p0] = acc[0][mt];
            *(f32x4*)&Pb[(size_t)(l16 + 16) * NF + p0] = acc[1][mt];
            if (l16 == 0) *(f32x4*)&Pb[(size_t)32 * NF + p0] = acc[2][mt];
        }
    }
}

// ---------------------------------------------------------------------------
// AR: sum Kc partial planes, fold A2=0.5 into quadratic rows, cvt->fp16 Gt
// ---------------------------------------------------------------------------
__global__ __launch_bounds__(256)
void ar_kernel(const float* __restrict__ P, half_t* __restrict__ Gt, int Kc)
{
    const int NP4 = NBH * NE * NF / 4;   // 287232
    const int idx = blockIdx.x * 256 + threadIdx.x;
    if (idx >= NP4) return;
    f32x4 a = *(const f32x4*)&P[(size_t)idx * 4];
    for (int c = 1; c < Kc; ++c)
        a += *(const f32x4*)&P[(size_t)c * NBH * NE * NF + (size_t)idx * 4];
    int row = idx / 272;                 // (bh*33 + e)
    int p4 = idx - row * 272;
    float s = (p4 >= 8 && p4 < 264) ? 0.5f : 1.0f;   // p in [32,1056): *0.5
    int e = row % 33, bhh = row / 33;
    half4v h = {(half_t)(a[0] * s), (half_t)(a[1] * s),
                (half_t)(a[2] * s), (half_t)(a[3] * s)};
    *(half4v*)&Gt[((size_t)(bhh * GE + e)) * NF + p4 * 4] = h;
}

// ---------------------------------------------------------------------------
// B: out[n][e] = (phi(q_n).G[:,e]) / (phi(q_n).G[:,32]) via f16 MFMA.
// A-frag: vq (8 consecutive q dims, preloaded) * scalar q_i from LDS.
// B-frags streamed from global Gt (L2 broadcast across 16 blocks/bh).
// ---------------------------------------------------------------------------
__global__ __launch_bounds__(256)
void b_kernel(const float* __restrict__ qin, const half_t* __restrict__ Gt,
              float* __restrict__ out)
{
    const int mbq = blockIdx.x, bh = blockIdx.y;
    const int t = threadIdx.x, w = t >> 6, lane = t & 63;
    const int l16 = lane & 15, quad = lane >> 4;
    __shared__ half_t qs[256 * 40];     // pad 32->40 halves: conflict-free
    __shared__ float denl[256];
    const size_t nbase = (size_t)bh * NTOK + mbq * 256;

    const float4* q4 = (const float4*)(qin + nbase * 32);
    #pragma unroll
    for (int r = 0; r < 8; ++r) {
        int f4 = t + 256 * r, n = f4 >> 3, d4 = f4 & 7;
        float4 vv = q4[f4];
        half4v h = {(half_t)vv.x, (half_t)vv.y, (half_t)vv.z, (half_t)vv.w};
        *(half4v*)&qs[n * 40 + d4 * 4] = h;
    }
    __syncthreads();

    const int rbase = w * 64;
    half8 vq[4];
    #pragma unroll
    for (int mt = 0; mt < 4; ++mt)
        vq[mt] = *(const half8*)&qs[(rbase + mt * 16 + l16) * 40 + quad * 8];

    f32x4 acc[3][4];
    #pragma unroll
    for (int a = 0; a < 3; ++a)
        #pragma unroll
        for (int b = 0; b < 4; ++b)
            acc[a][b] = (f32x4){0.f, 0.f, 0.f, 0.f};

    const half_t* Gb = Gt + (size_t)bh * GE * NF;
    const int koff = quad * 8;
    half8 b0 = *(const half8*)&Gb[(size_t)l16 * NF + koff];
    half8 b1 = *(const half8*)&Gb[(size_t)(l16 + 16) * NF + koff];
    half8 b2 = *(const half8*)&Gb[(size_t)(l16 + 32) * NF + koff];
    #pragma unroll 1
    for (int kt = 0; kt <= 32; ++kt) {
        half8 nb0 = b0, nb1 = b1, nb2 = b2;
        if (kt < 32) {                   // prefetch next k-tile's B-frags
            int o = (kt + 1) * 32 + koff;
            nb0 = *(const half8*)&Gb[(size_t)l16 * NF + o];
            nb1 = *(const half8*)&Gb[(size_t)(l16 + 16) * NF + o];
            nb2 = *(const half8*)&Gb[(size_t)(l16 + 32) * NF + o];
        }
        half8 af[4];
        if (kt == 0) {                   // linear features: phi = q_j
            #pragma unroll
            for (int mt = 0; mt < 4; ++mt) af[mt] = vq[mt];
        } else {                         // quadratic: phi = q_i * q_j (0.5 in Gt)
            const int i = kt - 1;
            #pragma unroll
            for (int mt = 0; mt < 4; ++mt) {
                half_t s = qs[(rbase + mt * 16 + l16) * 40 + i];
                af[mt] = vq[mt] * s;
            }
        }
        #pragma unroll
        for (int mt = 0; mt < 4; ++mt) {
            acc[0][mt] = MFMA16(af[mt], b0, acc[0][mt]);
            acc[1][mt] = MFMA16(af[mt], b1, acc[1][mt]);
            acc[2][mt] = MFMA16(af[mt], b2, acc[2][mt]);
        }
        b0 = nb0; b1 = nb1; b2 = nb2;
    }
    // constant feature row p=1056: adds v0[e] to num, 4096 to den
    float g0 = (float)Gb[(size_t)l16 * NF + 1056];
    float g1 = (float)Gb[(size_t)(l16 + 16) * NF + 1056];
    float g2 = (float)Gb[(size_t)(l16 + 32) * NF + 1056];
    #pragma unroll
    for (int mt = 0; mt < 4; ++mt)
        #pragma unroll
        for (int r = 0; r < 4; ++r) {
            acc[0][mt][r] += g0; acc[1][mt][r] += g1; acc[2][mt][r] += g2;
        }
    // broadcast den (col 32 lives in l16==0 lanes) via LDS
    if (l16 == 0) {
        #pragma unroll
        for (int mt = 0; mt < 4; ++mt)
            #pragma unroll
            for (int r = 0; r < 4; ++r)
                denl[rbase + mt * 16 + quad * 4 + r] = acc[2][mt][r];
    }
    __syncthreads();
    #pragma unroll
    for (int mt = 0; mt < 4; ++mt) {
        float inv[4];
        #pragma unroll
        for (int r = 0; r < 4; ++r)
            inv[r] = __builtin_amdgcn_rcpf(denl[rbase + mt * 16 + quad * 4 + r]);
        #pragma unroll
        for (int r = 0; r < 4; ++r) {
            size_t ro = (nbase + rbase + mt * 16 + quad * 4 + r) * 32;
            out[ro + l16] = acc[0][mt][r] * inv[r];
            out[ro + l16 + 16] = acc[1][mt][r] * inv[r];
        }
    }
}

// ---------------------------------------------------------------------------
extern "C" void kernel_launch(void* const* d_in, const int* in_sizes, int n_in,
                              void* d_out, int out_size, void* d_ws, size_t ws_size,
                              hipStream_t stream)
{
    const float* q = (const float*)d_in[0];
    const float* k = (const float*)d_in[1];
    const float* v = (const float*)d_in[2];
    float* out = (float*)d_out;

    const size_t planeBytes = (size_t)NBH * NE * NF * 4;   // 4,595,712
    const size_t ktBytes = (size_t)NBH * 32 * NTOK * 2;    // 8,388,608
    const size_t gtBytes = (size_t)NBH * GE * NF * 2;      // 3,342,336
    int Kc = 4;
    while (Kc > 1 && (Kc * planeBytes + 2 * ktBytes + gtBytes) > ws_size) Kc >>= 1;

    float* P = (float*)d_ws;
    half_t* kTg = (half_t*)((char*)d_ws + (size_t)Kc * planeBytes);
    half_t* vTg = kTg + (size_t)NBH * 32 * NTOK;
    half_t* Gt = vTg + (size_t)NBH * 32 * NTOK;

    t_kernel<<<dim3(16, NBH), 256, 0, stream>>>(k, v, kTg, vTg);
    a_kernel<<<dim3(5, Kc, NBH), 256, 0, stream>>>(kTg, vTg, P, Kc);
    ar_kernel<<<1122, 256, 0, stream>>>(P, Gt, Kc);
    b_kernel<<<dim3(16, NBH), 256, 0, stream>>>(q, Gt, out);
}

// Round 4
// 153.543 us; speedup vs baseline: 2.7657x; 1.0942x over previous
//
#include <hip/hip_runtime.h>

#define NTOK 4096
#define NBH  32
#define NF   1088   // features: 32 linear + 1024 quadratic + 1 const + 31 pad
#define NE   33     // stored G columns: 32 v-cols + 1 ones-col (denominator)
#define GE   48     // Gt row-count stride (rows 33..47 never written/used)

typedef _Float16 half_t;
typedef _Float16 half8 __attribute__((ext_vector_type(8)));
typedef _Float16 half4v __attribute__((ext_vector_type(4)));
typedef float f32x4 __attribute__((ext_vector_type(4)));
typedef unsigned int u32;

#define MFMA16(A,B,C) __builtin_amdgcn_mfma_f32_16x16x32_f16((A),(B),(C),0,0,0)

// async 16B global->LDS: lds dst = wave-uniform base + lane*16
#define ASYNC_CP16(dst_lds, src_glb) \
    __builtin_amdgcn_global_load_lds( \
        (const __attribute__((address_space(1))) u32*)(const void*)(src_glb), \
        (__attribute__((address_space(3))) u32*)(void*)(dst_lds), 16, 0, 0)

// ---------------------------------------------------------------------------
// T: transpose + fp32->fp16  k,v [bh][n][32] -> [bh][32][n]
// ---------------------------------------------------------------------------
__global__ __launch_bounds__(256)
void t_kernel(const float* __restrict__ kin, const float* __restrict__ vin,
              half_t* __restrict__ kTg, half_t* __restrict__ vTg)
{
    const int nb = blockIdx.x;     // 16 blocks of 256 n
    const int bh = blockIdx.y;
    const int t  = threadIdx.x;
    __shared__ __align__(16) half_t tile[32 * 272];
    const size_t inbase = ((size_t)bh * NTOK + nb * 256) * 32;

    for (int pass = 0; pass < 2; ++pass) {
        const float* src = pass ? vin : kin;
        half_t* dstg     = pass ? vTg : kTg;
        if (pass) __syncthreads();
        const float4* s4 = (const float4*)(src + inbase);
        #pragma unroll
        for (int r = 0; r < 8; ++r) {
            int f4 = t + 256 * r;
            int n = f4 >> 3, d4 = f4 & 7;
            float4 vv = s4[f4];
            int nn = n ^ ((d4 & 7) << 3);
            int d0 = d4 * 4;
            tile[(d0 + 0) * 272 + nn] = (half_t)vv.x;
            tile[(d0 + 1) * 272 + nn] = (half_t)vv.y;
            tile[(d0 + 2) * 272 + nn] = (half_t)vv.z;
            tile[(d0 + 3) * 272 + nn] = (half_t)vv.w;
        }
        __syncthreads();
        #pragma unroll
        for (int cc = 0; cc < 4; ++cc) {
            int lin = t + 256 * cc;
            int d = lin >> 5, ch = lin & 31;
            int sw = (d >> 2) & 7;
            half8 val = *(const half8*)&tile[d * 272 + ((ch ^ sw) << 3)];
            *(half8*)&dstg[((size_t)bh * 32 + d) * NTOK + nb * 256 + ch * 8] = val;
        }
    }
}

// ---------------------------------------------------------------------------
// A: G[p][e] = sum_n phi(k_n)[p] * [v_n | 1][e]  via f16 MFMA.
// Staging: global_load_lds width=16 into unpadded [32][128] tiles with
// chunk-XOR swizzle (phys = part ^ (row&15)) -> conflict-balanced b128 reads.
// Grid: x = kc*NBH+bh (slice), y = mb (0..4). Blocks sharing a slice are
// gridDim.x apart -> same XCD -> mb>0 reads hit L2.
// ---------------------------------------------------------------------------
__global__ __launch_bounds__(256)
void a_kernel(const half_t* __restrict__ kTg, const half_t* __restrict__ vTg,
              float* __restrict__ P, int Kc)
{
    const int x  = blockIdx.x;
    const int bh = x & (NBH - 1);
    const int kc = x >> 5;
    const int mb = blockIdx.y;   // 0..4 : 256 features each (mb4: only w0 real)
    const int t = threadIdx.x;
    const int w = t >> 6, lane = t & 63, l16 = lane & 15, quad = lane >> 4;

    __shared__ __align__(16) half_t kT[32 * 128];
    __shared__ __align__(16) half_t vT[32 * 128];

    const int pw = mb * 256 + w * 64;
    const bool active = (pw < NF);
    const int mode = (mb == 0 && w == 0) ? 1 : ((mb == 4) ? 2 : 0);
    const int i0 = (pw >= 32 && pw < NF) ? ((pw - 32) >> 5) : 0;

    f32x4 acc[3][4];
    #pragma unroll
    for (int a = 0; a < 3; ++a)
        #pragma unroll
        for (int b = 0; b < 4; ++b)
            acc[a][b] = (f32x4){0.f, 0.f, 0.f, 0.f};

    const size_t gbase = (size_t)bh * 32 * NTOK;
    const int nPer = NTOK / Kc;
    const int nStages = nPer >> 7;

    // per-thread staging source (row, part) for the 2 issues
    const int c0 = t,        r0 = c0 >> 4, p0s = (c0 & 15) ^ (r0 & 15);
    const int c1 = 256 + t,  r1 = c1 >> 4, p1s = (c1 & 15) ^ (r1 & 15);

    for (int st = 0; st < nStages; ++st) {
        __syncthreads();
        const int nbase = kc * nPer + st * 128;
        {
            const half_t* gk0 = kTg + gbase + (size_t)r0 * NTOK + nbase + p0s * 8;
            const half_t* gk1 = kTg + gbase + (size_t)r1 * NTOK + nbase + p1s * 8;
            const half_t* gv0 = vTg + gbase + (size_t)r0 * NTOK + nbase + p0s * 8;
            const half_t* gv1 = vTg + gbase + (size_t)r1 * NTOK + nbase + p1s * 8;
            ASYNC_CP16(kT + (size_t)w * 512,        gk0);
            ASYNC_CP16(kT + 2048 + (size_t)w * 512, gk1);
            ASYNC_CP16(vT + (size_t)w * 512,        gv0);
            ASYNC_CP16(vT + 2048 + (size_t)w * 512, gv1);
        }
        __syncthreads();
        if (!active) continue;
        #pragma unroll
        for (int kk = 0; kk < 4; ++kk) {
            const int c = kk * 4 + quad;               // logical chunk col
            const int offL = l16 * 128 + ((c ^ l16) << 3);
            const int offH = (l16 + 16) * 128 + ((c ^ l16) << 3);
            half8 bf0 = *(const half8*)&vT[offL];
            half8 bf1 = *(const half8*)&vT[offH];
            half_t onec = (l16 == 0) ? (half_t)1 : (half_t)0;
            half8 bf2 = {onec, onec, onec, onec, onec, onec, onec, onec};
            half8 kj0 = *(const half8*)&kT[offL];
            half8 kj1 = *(const half8*)&kT[offH];
            half8 af[4];
            bool skip3 = false;
            if (mode == 1) {            // p 0..63: linear tiles + i=0 quads
                half8 ki = *(const half8*)&kT[(c ^ 0) << 3];
                af[0] = kj0; af[1] = kj1;
                af[2] = ki * kj0; af[3] = ki * kj1;
            } else if (mode == 2) {     // p 1024..1087: i=31, const, skip
                half8 ki = *(const half8*)&kT[31 * 128 + ((c ^ 15) << 3)];
                af[0] = ki * kj0; af[1] = ki * kj1;
                af[2] = bf2;            // const feature row 1056 (l16==0)
                af[3] = bf2;
                skip3 = true;
            } else {
                half8 kia = *(const half8*)&kT[i0 * 128 + ((c ^ (i0 & 15)) << 3)];
                half8 kib = *(const half8*)&kT[(i0 + 1) * 128 + ((c ^ ((i0 + 1) & 15)) << 3)];
                af[0] = kia * kj0; af[1] = kia * kj1;
                af[2] = kib * kj0; af[3] = kib * kj1;
            }
            #pragma unroll
            for (int mt = 0; mt < 4; ++mt) {
                if (skip3 && mt == 3) continue;
                acc[0][mt] = MFMA16(af[mt], bf0, acc[0][mt]);
                acc[1][mt] = MFMA16(af[mt], bf1, acc[1][mt]);
                acc[2][mt] = MFMA16(af[mt], bf2, acc[2][mt]);
            }
        }
    }
    if (active) {
        float* Pb = P + ((size_t)kc * NBH + bh) * NE * NF;
        #pragma unroll
        for (int mt = 0; mt < 4; ++mt) {
            int p0 = pw + mt * 16 + quad * 4;
            *(f32x4*)&Pb[(size_t)l16 * NF + p0] = acc[0][mt];
            *(f32x4*)&Pb[(size_t)(l16 + 16) * NF + p0] = acc[1][mt];
            if (l16 == 0) *(f32x4*)&Pb[(size_t)32 * NF + p0] = acc[2][mt];
        }
    }
}

// ---------------------------------------------------------------------------
// AR: sum Kc partial planes, fold A2=0.5 into quadratic rows, cvt->fp16 Gt
// ---------------------------------------------------------------------------
__global__ __launch_bounds__(256)
void ar_kernel(const float* __restrict__ P, half_t* __restrict__ Gt, int Kc)
{
    const int NP4 = NBH * NE * NF / 4;   // 287232
    const int idx = blockIdx.x * 256 + threadIdx.x;
    if (idx >= NP4) return;
    f32x4 a = *(const f32x4*)&P[(size_t)idx * 4];
    for (int c = 1; c < Kc; ++c)
        a += *(const f32x4*)&P[(size_t)c * NBH * NE * NF + (size_t)idx * 4];
    int row = idx / 272;                 // (bh*33 + e)
    int p4 = idx - row * 272;
    float s = (p4 >= 8 && p4 < 264) ? 0.5f : 1.0f;   // p in [32,1056): *0.5
    int e = row % 33, bhh = row / 33;
    half4v h = {(half_t)(a[0] * s), (half_t)(a[1] * s),
                (half_t)(a[2] * s), (half_t)(a[3] * s)};
    *(half4v*)&Gt[((size_t)(bhh * GE + e)) * NF + p4 * 4] = h;
}

// ---------------------------------------------------------------------------
// B: out[n][e] = (phi(q_n).G[:,e]) / (phi(q_n).G[:,32]) via f16 MFMA.
// qsP[i][w][l16][mt] layout gives the 4 per-mt scalars in one ds_read_b64.
// Gt B-frags streamed from global with depth-2 prefetch ring.
// Grid: x = bh, y = mbq -> blocks of one bh are 32 apart -> same XCD L2.
// ---------------------------------------------------------------------------
__global__ __launch_bounds__(256)
void b_kernel(const float* __restrict__ qin, const half_t* __restrict__ Gt,
              float* __restrict__ out)
{
    const int bh = blockIdx.x, mbq = blockIdx.y;
    const int t = threadIdx.x, w = t >> 6, lane = t & 63;
    const int l16 = lane & 15, quad = lane >> 4;
    __shared__ __align__(16) half_t qs[256 * 40];   // row-major padded
    __shared__ __align__(16) half_t qsP[32 * 272];  // [i][w][l16][mt] padded
    __shared__ float denl[256];
    const size_t nbase = (size_t)bh * NTOK + mbq * 256;

    const float4* q4 = (const float4*)(qin + nbase * 32);
    #pragma unroll
    for (int r = 0; r < 8; ++r) {
        int f4 = t + 256 * r, n = f4 >> 3, d4 = f4 & 7;
        float4 vv = q4[f4];
        half4v h = {(half_t)vv.x, (half_t)vv.y, (half_t)vv.z, (half_t)vv.w};
        *(half4v*)&qs[n * 40 + d4 * 4] = h;
        int pb = (n >> 6) * 64 + (n & 15) * 4 + ((n >> 4) & 3);
        qsP[(4 * d4 + 0) * 272 + pb] = h[0];
        qsP[(4 * d4 + 1) * 272 + pb] = h[1];
        qsP[(4 * d4 + 2) * 272 + pb] = h[2];
        qsP[(4 * d4 + 3) * 272 + pb] = h[3];
    }
    __syncthreads();

    const int rbase = w * 64;
    half8 vq[4];
    #pragma unroll
    for (int mt = 0; mt < 4; ++mt)
        vq[mt] = *(const half8*)&qs[(rbase + mt * 16 + l16) * 40 + quad * 8];

    f32x4 acc[3][4];
    #pragma unroll
    for (int a = 0; a < 3; ++a)
        #pragma unroll
        for (int b = 0; b < 4; ++b)
            acc[a][b] = (f32x4){0.f, 0.f, 0.f, 0.f};

    const half_t* Gb = Gt + (size_t)bh * GE * NF;
    const int koff = quad * 8;
    const int sOff = w * 64 + l16 * 4;

    half8 B0[3], B1[3], B2[3];
    #pragma unroll
    for (int rr = 0; rr < 3; ++rr) {
        B0[rr] = *(const half8*)&Gb[(size_t)(l16 + 16 * rr) * NF + koff];
        B1[rr] = *(const half8*)&Gb[(size_t)(l16 + 16 * rr) * NF + 32 + koff];
    }

    #pragma unroll 1
    for (int kt = 0; kt <= 32; ++kt) {
        const int ktn = (kt + 2 <= 32) ? kt + 2 : 32;
        const int o = ktn * 32 + koff;
        #pragma unroll
        for (int rr = 0; rr < 3; ++rr)
            B2[rr] = *(const half8*)&Gb[(size_t)(l16 + 16 * rr) * NF + o];

        half8 af[4];
        if (kt == 0) {                   // linear features: phi = q_j
            #pragma unroll
            for (int mt = 0; mt < 4; ++mt) af[mt] = vq[mt];
        } else {                         // quadratic: phi = q_i * q_j
            const int i = kt - 1;
            half4v sv = *(const half4v*)&qsP[i * 272 + sOff];
            #pragma unroll
            for (int mt = 0; mt < 4; ++mt)
                af[mt] = vq[mt] * sv[mt];
        }
        #pragma unroll
        for (int mt = 0; mt < 4; ++mt) {
            acc[0][mt] = MFMA16(af[mt], B0[0], acc[0][mt]);
            acc[1][mt] = MFMA16(af[mt], B0[1], acc[1][mt]);
            acc[2][mt] = MFMA16(af[mt], B0[2], acc[2][mt]);
        }
        #pragma unroll
        for (int rr = 0; rr < 3; ++rr) { B0[rr] = B1[rr]; B1[rr] = B2[rr]; }
    }
    // constant feature row p=1056: adds v0[e] to num, 4096 to den
    float g0 = (float)Gb[(size_t)l16 * NF + 1056];
    float g1 = (float)Gb[(size_t)(l16 + 16) * NF + 1056];
    float g2 = (float)Gb[(size_t)(l16 + 32) * NF + 1056];
    #pragma unroll
    for (int mt = 0; mt < 4; ++mt)
        #pragma unroll
        for (int r = 0; r < 4; ++r) {
            acc[0][mt][r] += g0; acc[1][mt][r] += g1; acc[2][mt][r] += g2;
        }
    // broadcast den (col 32 lives in l16==0 lanes) via LDS
    if (l16 == 0) {
        #pragma unroll
        for (int mt = 0; mt < 4; ++mt)
            #pragma unroll
            for (int r = 0; r < 4; ++r)
                denl[rbase + mt * 16 + quad * 4 + r] = acc[2][mt][r];
    }
    __syncthreads();
    #pragma unroll
    for (int mt = 0; mt < 4; ++mt) {
        float inv[4];
        #pragma unroll
        for (int r = 0; r < 4; ++r)
            inv[r] = __builtin_amdgcn_rcpf(denl[rbase + mt * 16 + quad * 4 + r]);
        #pragma unroll
        for (int r = 0; r < 4; ++r) {
            size_t ro = (nbase + rbase + mt * 16 + quad * 4 + r) * 32;
            out[ro + l16] = acc[0][mt][r] * inv[r];
            out[ro + l16 + 16] = acc[1][mt][r] * inv[r];
        }
    }
}

// ---------------------------------------------------------------------------
extern "C" void kernel_launch(void* const* d_in, const int* in_sizes, int n_in,
                              void* d_out, int out_size, void* d_ws, size_t ws_size,
                              hipStream_t stream)
{
    const float* q = (const float*)d_in[0];
    const float* k = (const float*)d_in[1];
    const float* v = (const float*)d_in[2];
    float* out = (float*)d_out;

    const size_t planeBytes = (size_t)NBH * NE * NF * 4;   // 4,595,712
    const size_t ktBytes = (size_t)NBH * 32 * NTOK * 2;    // 8,388,608
    const size_t gtBytes = (size_t)NBH * GE * NF * 2;      // 3,342,336
    int Kc = 8;
    while (Kc > 1 && ((size_t)Kc * planeBytes + 2 * ktBytes + gtBytes) > ws_size)
        Kc >>= 1;

    float* P = (float*)d_ws;
    half_t* kTg = (half_t*)((char*)d_ws + (size_t)Kc * planeBytes);
    half_t* vTg = kTg + (size_t)NBH * 32 * NTOK;
    half_t* Gt = vTg + (size_t)NBH * 32 * NTOK;

    t_kernel<<<dim3(16, NBH), 256, 0, stream>>>(k, v, kTg, vTg);
    a_kernel<<<dim3(Kc * NBH, 5), 256, 0, stream>>>(kTg, vTg, P, Kc);
    ar_kernel<<<1122, 256, 0, stream>>>(P, Gt, Kc);
    b_kernel<<<dim3(NBH, 16), 256, 0, stream>>>(q, Gt, out);
}